// Round 1
// baseline (204.848 us; speedup 1.0000x reference)
//
#include <hip/hip_runtime.h>

// Batched 2D db4 DWT (pywt dwt2, mode='symmetric') over [8,32,512,512] f32.
// Output [4, 8, 32, 259, 259] f32 (LL, LH, HL, HH).
//
// Derivation from the reference:
//   ext = symmetric-pad(x, 7, 7); xp = ext[1:]
//   y[o] = sum_t xp[2o+t] * F_rev[t] = sum_k ext[2o+1+k] * F[7-k],  o in [0,259)
// so with flipped filters G[k] = F[7-k]:  y[o] = sum_k ext[2o+1+k] * G[k].
// ext index -> source index (n=512):  j<7 -> 6-j ; j<=518 -> j-7 ; else 1030-j.

namespace {

constexpr int N   = 512;         // input H == W
constexpr int HO  = 259;         // output H == W per subband  (floor((512+7)/2))
constexpr int TO  = 32;          // output tile edge (per subband)
constexpr int TI  = 2 * TO + 6;  // 70: input span needed for TO outputs
constexpr int TIS = 73;          // LDS stride for input tile (odd: breaks stride-2 conflicts)
constexpr int MS  = TO + 1;      // 33: LDS stride for mid arrays
constexpr int NBC = 8 * 32;      // 256 images

// Flipped db4 decomposition filters: GL[k] = DEC_LO[7-k], GH[k] = DEC_HI[7-k]
__device__ constexpr float GL[8] = {
     0.23037781330885523f,  0.7148465705525415f,   0.6308807679295904f,
    -0.02798376941698385f, -0.18703481171888114f,  0.030841381835986965f,
     0.032883011666982945f,-0.010597401784997278f};
__device__ constexpr float GH[8] = {
    -0.010597401784997278f,-0.032883011666982945f, 0.030841381835986965f,
     0.18703481171888114f, -0.02798376941698385f, -0.6308807679295904f,
     0.7148465705525415f,  -0.23037781330885523f};

__device__ __forceinline__ int ext_idx(int j) {
    // symmetric ("half-sample") extension map, n = 512, pad = 7 each side.
    int v = j - 7;                       // interior
    v = (j < 7)     ? (6 - j)        : v; // left reflect
    v = (j > N + 6) ? (2 * N + 6 - j) : v; // right reflect (safe for tile overhang)
    return v;
}

__global__ __launch_bounds__(256)
void dwt2_db4(const float* __restrict__ x, float* __restrict__ out) {
    __shared__ float tile[TI][TIS];
    __shared__ float midlo[TI][MS];
    __shared__ float midhi[TI][MS];

    const int bc  = blockIdx.z;
    const int ho0 = blockIdx.y * TO;
    const int wo0 = blockIdx.x * TO;
    const int eh0 = 2 * ho0 + 1;
    const int ew0 = 2 * wo0 + 1;
    const int t   = threadIdx.x;

    const float* __restrict__ img = x + (size_t)bc * (N * N);

    // ---- stage input tile with symmetric extension applied ----
    for (int e = t; e < TI * TI; e += 256) {
        const int r = e / TI;
        const int c = e - r * TI;
        tile[r][c] = img[ext_idx(eh0 + r) * N + ext_idx(ew0 + c)];
    }
    __syncthreads();

    // ---- W (horizontal) pass: 70 rows x 32 output cols, lo+hi ----
    for (int e = t; e < TI * TO; e += 256) {
        const int r  = e >> 5;        // TO == 32
        const int ow = e & (TO - 1);
        float lo = 0.f, hi = 0.f;
        #pragma unroll
        for (int k = 0; k < 8; ++k) {
            const float v = tile[r][2 * ow + k];
            lo = fmaf(v, GL[k], lo);
            hi = fmaf(v, GH[k], hi);
        }
        midlo[r][ow] = lo;
        midhi[r][ow] = hi;
    }
    __syncthreads();

    // ---- H (vertical) pass + store all 4 subbands ----
    const size_t sub   = (size_t)NBC * HO * HO;          // per-subband stride
    float* __restrict__ obase = out + (size_t)bc * (HO * HO);
    const int ow = t & 31;
    const int wo = wo0 + ow;
    #pragma unroll
    for (int i = 0; i < 4; ++i) {
        const int oh = (t >> 5) + 8 * i;
        const int ho = ho0 + oh;
        if (ho < HO && wo < HO) {
            float ll = 0.f, lh = 0.f, hl = 0.f, hh = 0.f;
            #pragma unroll
            for (int k = 0; k < 8; ++k) {
                const float a = midlo[2 * oh + k][ow];
                const float d = midhi[2 * oh + k][ow];
                ll = fmaf(a, GL[k], ll);
                lh = fmaf(a, GH[k], lh);
                hl = fmaf(d, GL[k], hl);
                hh = fmaf(d, GH[k], hh);
            }
            const size_t p = (size_t)ho * HO + wo;
            obase[p]           = ll;
            obase[sub + p]     = lh;
            obase[2 * sub + p] = hl;
            obase[3 * sub + p] = hh;
        }
    }
}

} // namespace

extern "C" void kernel_launch(void* const* d_in, const int* in_sizes, int n_in,
                              void* d_out, int out_size, void* d_ws, size_t ws_size,
                              hipStream_t stream) {
    const float* x = (const float*)d_in[0];
    float* out = (float*)d_out;
    const int tiles = (HO + TO - 1) / TO;   // 9
    dim3 grid(tiles, tiles, NBC);           // (9, 9, 256)
    dwt2_db4<<<grid, 256, 0, stream>>>(x, out);
}

// Round 2
// 162.050 us; speedup vs baseline: 1.2641x; 1.2641x over previous
//
#include <hip/hip_runtime.h>

// Batched 2D db4 DWT (pywt dwt2, mode='symmetric') over [8,32,512,512] f32.
// Output [4, 8, 32, 259, 259] f32 (LL, LH, HL, HH).
//
//   y[o] = sum_k ext[2o+1+k] * G[k],  G[k] = F[7-k]
//   ext index j -> src:  j<7 -> 6-j ; j<=518 -> j-7 ; else 1030-j
//
// v2: no input LDS tile. W-pass reads global directly (vector loads) into
// registers, writes lo/hi mid rows to LDS as float4. H-pass reads mid as
// float4 (stride 68 floats = 17*16B, bank-balanced), stores float4/subband.

namespace {

constexpr int N   = 512;
constexpr int HO  = 259;
constexpr int TOH = 32;          // output rows per tile
constexpr int TOW = 64;          // output cols per tile
constexpr int TIH = 2 * TOH + 6; // 70 mid rows
constexpr int MS  = TOW + 4;     // 68: mid LDS stride (272B = 17*16B)
constexpr int NBC = 256;         // images

// reduced-alignment float4 for 8B-aligned global loads
typedef float f4 __attribute__((ext_vector_type(4)));
typedef f4 __attribute__((aligned(4))) f4u;
typedef float f2 __attribute__((ext_vector_type(2)));
typedef f2 __attribute__((aligned(4))) f2u;

__device__ constexpr float GL[8] = {
     0.23037781330885523f,  0.7148465705525415f,   0.6308807679295904f,
    -0.02798376941698385f, -0.18703481171888114f,  0.030841381835986965f,
     0.032883011666982945f,-0.010597401784997278f};
__device__ constexpr float GH[8] = {
    -0.010597401784997278f,-0.032883011666982945f, 0.030841381835986965f,
     0.18703481171888114f, -0.02798376941698385f, -0.6308807679295904f,
     0.7148465705525415f,  -0.23037781330885523f};

__device__ __forceinline__ int ext_idx(int j) {
    int v = j - 7;
    v = (j < 7)     ? (6 - j)         : v;
    v = (j > N + 6) ? (2 * N + 6 - j) : v;
    return v;
}

__global__ __launch_bounds__(256)
void dwt2_db4(const float* __restrict__ x, float* __restrict__ out) {
    __shared__ __align__(16) float midlo[TIH][MS];
    __shared__ __align__(16) float midhi[TIH][MS];

    const int bc  = blockIdx.z;
    const int ho0 = blockIdx.y * TOH;
    const int wo0 = blockIdx.x * TOW;
    const int eh0 = 2 * ho0 + 1;
    const int t   = threadIdx.x;
    const int ru  = min(TOH, HO - ho0);       // output rows used
    const int cu  = min(TOW, HO - wo0);       // output cols used
    const int rmax = 2 * ru + 6;              // mid rows needed
    const int qmax = (cu + 3) >> 2;           // mid col-groups needed

    const float* __restrict__ img = x + (size_t)bc * (N * N);

    // ---- W-pass: global -> regs -> mid LDS. item = (mid row r, col-group q) ----
    for (int e = t; e < TIH * 16; e += 256) {
        const int r = e >> 4;
        const int q = e & 15;
        if (r >= rmax || q >= qmax) continue;
        const int gr = ext_idx(eh0 + r);
        const float* __restrict__ row = img + (size_t)gr * N;
        const int j0 = 2 * wo0 + 8 * q + 1;   // ext index of first tap
        const int g0 = j0 - 7;                // src col of first tap (interior)
        float v[14];
        if (g0 >= 0 && g0 <= N - 14) {        // fully interior in W
            const f4 a = *(const f4u*)(row + g0);
            const f4 b = *(const f4u*)(row + g0 + 4);
            const f4 c = *(const f4u*)(row + g0 + 8);
            const f2 d = *(const f2u*)(row + g0 + 12);
            v[0]=a.x; v[1]=a.y; v[2]=a.z; v[3]=a.w;
            v[4]=b.x; v[5]=b.y; v[6]=b.z; v[7]=b.w;
            v[8]=c.x; v[9]=c.y; v[10]=c.z; v[11]=c.w;
            v[12]=d.x; v[13]=d.y;
        } else {
            #pragma unroll
            for (int f = 0; f < 14; ++f) v[f] = row[ext_idx(j0 + f)];
        }
        f4 lo, hi;
        #pragma unroll
        for (int o = 0; o < 4; ++o) {
            float l = 0.f, h = 0.f;
            #pragma unroll
            for (int k = 0; k < 8; ++k) {
                l = fmaf(v[2 * o + k], GL[k], l);
                h = fmaf(v[2 * o + k], GH[k], h);
            }
            lo[o] = l; hi[o] = h;
        }
        *(f4*)&midlo[r][4 * q] = lo;
        *(f4*)&midhi[r][4 * q] = hi;
    }
    __syncthreads();

    // ---- H-pass: thread = (col-group cg, row-group rg): 4 cols x 2 rows ----
    const int cg = t & 15;
    const int rg = t >> 4;
    const int c0 = 4 * cg;
    const size_t sub = (size_t)NBC * HO * HO;
    float* __restrict__ obase = out + (size_t)bc * (HO * HO);

    #pragma unroll
    for (int j = 0; j < 2; ++j) {
        const int ohl = 2 * rg + j;
        if (ohl >= ru || c0 >= cu) continue;
        f4 ll = {0,0,0,0}, lh = {0,0,0,0}, hl = {0,0,0,0}, hh = {0,0,0,0};
        const int rbase = 2 * ohl;
        #pragma unroll
        for (int k = 0; k < 8; ++k) {
            const f4 a = *(const f4*)&midlo[rbase + k][c0];
            const f4 d = *(const f4*)&midhi[rbase + k][c0];
            const float gl = GL[k], gh = GH[k];
            ll.x = fmaf(a.x, gl, ll.x); ll.y = fmaf(a.y, gl, ll.y);
            ll.z = fmaf(a.z, gl, ll.z); ll.w = fmaf(a.w, gl, ll.w);
            lh.x = fmaf(a.x, gh, lh.x); lh.y = fmaf(a.y, gh, lh.y);
            lh.z = fmaf(a.z, gh, lh.z); lh.w = fmaf(a.w, gh, lh.w);
            hl.x = fmaf(d.x, gl, hl.x); hl.y = fmaf(d.y, gl, hl.y);
            hl.z = fmaf(d.z, gl, hl.z); hl.w = fmaf(d.w, gl, hl.w);
            hh.x = fmaf(d.x, gh, hh.x); hh.y = fmaf(d.y, gh, hh.y);
            hh.z = fmaf(d.z, gh, hh.z); hh.w = fmaf(d.w, gh, hh.w);
        }
        const int ho = ho0 + ohl;
        const size_t p = (size_t)ho * HO + wo0 + c0;
        if (c0 + 3 < cu) {
            *(f4u*)(obase + p)           = ll;
            *(f4u*)(obase + sub + p)     = lh;
            *(f4u*)(obase + 2 * sub + p) = hl;
            *(f4u*)(obase + 3 * sub + p) = hh;
        } else {
            for (int o = 0; o < 4; ++o) {
                if (c0 + o < cu) {
                    obase[p + o]           = ll[o];
                    obase[sub + p + o]     = lh[o];
                    obase[2 * sub + p + o] = hl[o];
                    obase[3 * sub + p + o] = hh[o];
                }
            }
        }
    }
}

} // namespace

extern "C" void kernel_launch(void* const* d_in, const int* in_sizes, int n_in,
                              void* d_out, int out_size, void* d_ws, size_t ws_size,
                              hipStream_t stream) {
    const float* x = (const float*)d_in[0];
    float* out = (float*)d_out;
    const int tw = (HO + TOW - 1) / TOW;   // 5
    const int th = (HO + TOH - 1) / TOH;   // 9
    dim3 grid(tw, th, NBC);                // (5, 9, 256)
    dwt2_db4<<<grid, 256, 0, stream>>>(x, out);
}

// Round 3
// 158.268 us; speedup vs baseline: 1.2943x; 1.0239x over previous
//
#include <hip/hip_runtime.h>

// Batched 2D db4 DWT (pywt dwt2, mode='symmetric') over [8,32,512,512] f32.
// Output [4, 8, 32, 259, 259] f32 (LL, LH, HL, HH).
//
//   y[o] = sum_k ext[2o+1+k] * G[k],  G[k] = F[7-k]
//   ext index j -> src:  j<7 -> 6-j ; j<=518 -> j-7 ; else 1030-j
//
// v3: same structure as v2 but TOH=16 -> LDS 20.7KB -> 7 blocks/CU (87%
// occupancy theoretical vs 50%). W-pass reads global directly (vector loads),
// writes lo/hi mid rows to LDS as float4. H-pass: 1 output row x 4 cols per
// thread, float4 LDS reads (stride 68 floats), float4 stores per subband.

namespace {

constexpr int N   = 512;
constexpr int HO  = 259;
constexpr int TOH = 16;          // output rows per tile
constexpr int TOW = 64;          // output cols per tile
constexpr int TIH = 2 * TOH + 6; // 38 mid rows
constexpr int MS  = TOW + 4;     // 68: mid LDS stride (272B = 17*16B)
constexpr int NBC = 256;         // images

typedef float f4 __attribute__((ext_vector_type(4)));
typedef f4 __attribute__((aligned(4))) f4u;
typedef float f2 __attribute__((ext_vector_type(2)));
typedef f2 __attribute__((aligned(4))) f2u;

__device__ constexpr float GL[8] = {
     0.23037781330885523f,  0.7148465705525415f,   0.6308807679295904f,
    -0.02798376941698385f, -0.18703481171888114f,  0.030841381835986965f,
     0.032883011666982945f,-0.010597401784997278f};
__device__ constexpr float GH[8] = {
    -0.010597401784997278f,-0.032883011666982945f, 0.030841381835986965f,
     0.18703481171888114f, -0.02798376941698385f, -0.6308807679295904f,
     0.7148465705525415f,  -0.23037781330885523f};

__device__ __forceinline__ int ext_idx(int j) {
    int v = j - 7;
    v = (j < 7)     ? (6 - j)         : v;
    v = (j > N + 6) ? (2 * N + 6 - j) : v;
    return v;
}

__global__ __launch_bounds__(256)
void dwt2_db4(const float* __restrict__ x, float* __restrict__ out) {
    __shared__ __align__(16) float midlo[TIH][MS];
    __shared__ __align__(16) float midhi[TIH][MS];

    const int bc  = blockIdx.z;
    const int ho0 = blockIdx.y * TOH;
    const int wo0 = blockIdx.x * TOW;
    const int eh0 = 2 * ho0 + 1;
    const int t   = threadIdx.x;
    const int ru  = min(TOH, HO - ho0);       // output rows used
    const int cu  = min(TOW, HO - wo0);       // output cols used
    const int rmax = 2 * ru + 6;              // mid rows needed
    const int qmax = (cu + 3) >> 2;           // mid col-groups needed

    const float* __restrict__ img = x + (size_t)bc * (N * N);

    // ---- W-pass: global -> regs -> mid LDS. item = (mid row r, col-group q) ----
    #pragma unroll
    for (int e = t; e < TIH * 16; e += 256) {
        const int r = e >> 4;
        const int q = e & 15;
        if (r >= rmax || q >= qmax) continue;
        const int gr = ext_idx(eh0 + r);
        const float* __restrict__ row = img + (size_t)gr * N;
        const int j0 = 2 * wo0 + 8 * q + 1;   // ext index of first tap
        const int g0 = j0 - 7;                // src col of first tap (interior)
        float v[14];
        if (g0 >= 0 && g0 <= N - 14) {        // fully interior in W
            const f4 a = *(const f4u*)(row + g0);
            const f4 b = *(const f4u*)(row + g0 + 4);
            const f4 c = *(const f4u*)(row + g0 + 8);
            const f2 d = *(const f2u*)(row + g0 + 12);
            v[0]=a.x; v[1]=a.y; v[2]=a.z; v[3]=a.w;
            v[4]=b.x; v[5]=b.y; v[6]=b.z; v[7]=b.w;
            v[8]=c.x; v[9]=c.y; v[10]=c.z; v[11]=c.w;
            v[12]=d.x; v[13]=d.y;
        } else {
            #pragma unroll
            for (int f = 0; f < 14; ++f) v[f] = row[ext_idx(j0 + f)];
        }
        f4 lo, hi;
        #pragma unroll
        for (int o = 0; o < 4; ++o) {
            float l = 0.f, h = 0.f;
            #pragma unroll
            for (int k = 0; k < 8; ++k) {
                l = fmaf(v[2 * o + k], GL[k], l);
                h = fmaf(v[2 * o + k], GH[k], h);
            }
            lo[o] = l; hi[o] = h;
        }
        *(f4*)&midlo[r][4 * q] = lo;
        *(f4*)&midhi[r][4 * q] = hi;
    }
    __syncthreads();

    // ---- H-pass: thread = (col-group cg, row rg): 4 cols x 1 row ----
    const int cg = t & 15;
    const int rg = t >> 4;
    const int c0 = 4 * cg;
    const size_t sub = (size_t)NBC * HO * HO;
    float* __restrict__ obase = out + (size_t)bc * (HO * HO);

    if (rg < ru && c0 < cu) {
        f4 ll = {0,0,0,0}, lh = {0,0,0,0}, hl = {0,0,0,0}, hh = {0,0,0,0};
        const int rbase = 2 * rg;
        #pragma unroll
        for (int k = 0; k < 8; ++k) {
            const f4 a = *(const f4*)&midlo[rbase + k][c0];
            const f4 d = *(const f4*)&midhi[rbase + k][c0];
            const float gl = GL[k], gh = GH[k];
            ll.x = fmaf(a.x, gl, ll.x); ll.y = fmaf(a.y, gl, ll.y);
            ll.z = fmaf(a.z, gl, ll.z); ll.w = fmaf(a.w, gl, ll.w);
            lh.x = fmaf(a.x, gh, lh.x); lh.y = fmaf(a.y, gh, lh.y);
            lh.z = fmaf(a.z, gh, lh.z); lh.w = fmaf(a.w, gh, lh.w);
            hl.x = fmaf(d.x, gl, hl.x); hl.y = fmaf(d.y, gl, hl.y);
            hl.z = fmaf(d.z, gl, hl.z); hl.w = fmaf(d.w, gl, hl.w);
            hh.x = fmaf(d.x, gh, hh.x); hh.y = fmaf(d.y, gh, hh.y);
            hh.z = fmaf(d.z, gh, hh.z); hh.w = fmaf(d.w, gh, hh.w);
        }
        const int ho = ho0 + rg;
        const size_t p = (size_t)ho * HO + wo0 + c0;
        if (c0 + 3 < cu) {
            *(f4u*)(obase + p)           = ll;
            *(f4u*)(obase + sub + p)     = lh;
            *(f4u*)(obase + 2 * sub + p) = hl;
            *(f4u*)(obase + 3 * sub + p) = hh;
        } else {
            for (int o = 0; o < 4; ++o) {
                if (c0 + o < cu) {
                    obase[p + o]           = ll[o];
                    obase[sub + p + o]     = lh[o];
                    obase[2 * sub + p + o] = hl[o];
                    obase[3 * sub + p + o] = hh[o];
                }
            }
        }
    }
}

} // namespace

extern "C" void kernel_launch(void* const* d_in, const int* in_sizes, int n_in,
                              void* d_out, int out_size, void* d_ws, size_t ws_size,
                              hipStream_t stream) {
    const float* x = (const float*)d_in[0];
    float* out = (float*)d_out;
    const int tw = (HO + TOW - 1) / TOW;   // 5
    const int th = (HO + TOH - 1) / TOH;   // 17
    dim3 grid(tw, th, NBC);                // (5, 17, 256)
    dwt2_db4<<<grid, 256, 0, stream>>>(x, out);
}

// Round 4
// 143.831 us; speedup vs baseline: 1.4242x; 1.1004x over previous
//
#include <hip/hip_runtime.h>

// Batched 2D db4 DWT (pywt dwt2, mode='symmetric') over [8,32,512,512] f32.
// Output [4, 8, 32, 259, 259] f32 (LL, LH, HL, HH).
//
//   y[o] = sum_k ext[2o+1+k] * G[k],  G[k] = F[7-k]
//   ext index j -> src:  j<7 -> 6-j ; j<=518 -> j-7 ; else 1030-j
//
// v4: no LDS, no barriers. Thread = (image, 12-row output strip, 4-col group).
// Walks the strip vertically holding the last 8 horizontal-filter results
// (lo/hi, f4 each) in a statically-indexed register ring (4-step unroll makes
// all ring indices compile-time). 8 independent vector loads per output row
// give deep memory-level parallelism; zero ds ops, zero barriers.

namespace {

constexpr int N   = 512;
constexpr int HO  = 259;
constexpr int NBC = 256;
constexpr int TOH = 12;                     // output rows per strip
constexpr int NS  = (HO + TOH - 1) / TOH;   // 22 strips
constexpr int NCG = 65;                     // 4-col groups (65*4 = 260 >= 259)

typedef float f4 __attribute__((ext_vector_type(4)));
typedef f4 __attribute__((aligned(4))) f4u;
typedef float f2 __attribute__((ext_vector_type(2)));
typedef f2 __attribute__((aligned(4))) f2u;

__device__ constexpr float GL[8] = {
     0.23037781330885523f,  0.7148465705525415f,   0.6308807679295904f,
    -0.02798376941698385f, -0.18703481171888114f,  0.030841381835986965f,
     0.032883011666982945f,-0.010597401784997278f};
__device__ constexpr float GH[8] = {
    -0.010597401784997278f,-0.032883011666982945f, 0.030841381835986965f,
     0.18703481171888114f, -0.02798376941698385f, -0.6308807679295904f,
     0.7148465705525415f,  -0.23037781330885523f};

// Edge-lane tap->window permutations (window loaded from clamped base).
// cg==0  : window base 0,   v[f] = win[LMAP[f]]  (= row[ext_idx(1+f)])
// cg==64 : window base 498, v[f] = win[RMAP[f]]  (= row[ext_idx(513+f)])
__device__ constexpr int LMAP[14] = {5,4,3,2,1,0,0,1,2,3,4,5,6,7};
__device__ constexpr int RMAP[14] = {8,9,10,11,12,13,13,12,11,10,9,8,7,6};

__device__ __forceinline__ int ext_idx(int j) {
    int v = j - 7;
    v = (j < 7)     ? (6 - j)         : v;
    v = (j > N + 6) ? (2 * N + 6 - j) : v;
    return v;
}

__device__ __forceinline__ void hconv(const float* __restrict__ base, int mode,
                                      f4& lo, f4& hi) {
    const f4 a = *(const f4u*)(base);
    const f4 b = *(const f4u*)(base + 4);
    const f4 c = *(const f4u*)(base + 8);
    const f2 d = *(const f2u*)(base + 12);
    const float win[14] = {a.x,a.y,a.z,a.w, b.x,b.y,b.z,b.w,
                           c.x,c.y,c.z,c.w, d.x,d.y};
    float v[14];
    if (mode == 0) {
        #pragma unroll
        for (int f = 0; f < 14; ++f) v[f] = win[f];
    } else if (mode < 0) {
        #pragma unroll
        for (int f = 0; f < 14; ++f) v[f] = win[LMAP[f]];
    } else {
        #pragma unroll
        for (int f = 0; f < 14; ++f) v[f] = win[RMAP[f]];
    }
    #pragma unroll
    for (int o = 0; o < 4; ++o) {
        float l = 0.f, h = 0.f;
        #pragma unroll
        for (int k = 0; k < 8; ++k) {
            l = fmaf(v[2 * o + k], GL[k], l);
            h = fmaf(v[2 * o + k], GH[k], h);
        }
        lo[o] = l; hi[o] = h;
    }
}

__global__ __launch_bounds__(256)
void dwt2_db4_reg(const float* __restrict__ x, float* __restrict__ out) {
    const int id   = blockIdx.x * 256 + threadIdx.x;
    const int cg   = id % NCG;
    const int rest = id / NCG;
    const int st   = rest % NS;
    const int bc   = rest / NS;
    const int c0   = 4 * cg;
    const int g0   = 2 * c0 - 6;
    const int g0c  = min(max(g0, 0), N - 14);
    const int mode = (cg == 0) ? -1 : ((cg == NCG - 1) ? 1 : 0);
    const float* __restrict__ img = x + (size_t)bc * (N * N);
    const int eh0 = 2 * (st * TOH) + 1;

    f4 rlo[8], rhi[8];
    #pragma unroll
    for (int r = 0; r < 6; ++r)
        hconv(img + (size_t)ext_idx(eh0 + r) * N + g0c, mode, rlo[r], rhi[r]);

    const size_t sub = (size_t)NBC * HO * HO;
    float* __restrict__ obase = out + (size_t)bc * (HO * HO);

#define STEP(U) do {                                                          \
    const int uo_ = ob * 4 + (U);                                             \
    const int e_  = eh0 + 2 * uo_ + 6;                                        \
    hconv(img + (size_t)ext_idx(e_)     * N + g0c, mode,                      \
          rlo[(6 + 2 * (U)) & 7], rhi[(6 + 2 * (U)) & 7]);                    \
    hconv(img + (size_t)ext_idx(e_ + 1) * N + g0c, mode,                      \
          rlo[(7 + 2 * (U)) & 7], rhi[(7 + 2 * (U)) & 7]);                    \
    f4 ll = {0,0,0,0}, lh = {0,0,0,0}, hl = {0,0,0,0}, hh = {0,0,0,0};        \
    _Pragma("unroll")                                                         \
    for (int k = 0; k < 8; ++k) {                                             \
        const f4 a_ = rlo[(2 * (U) + k) & 7];                                 \
        const f4 d_ = rhi[(2 * (U) + k) & 7];                                 \
        const float gl = GL[k], gh = GH[k];                                   \
        ll.x = fmaf(a_.x, gl, ll.x); ll.y = fmaf(a_.y, gl, ll.y);             \
        ll.z = fmaf(a_.z, gl, ll.z); ll.w = fmaf(a_.w, gl, ll.w);             \
        lh.x = fmaf(a_.x, gh, lh.x); lh.y = fmaf(a_.y, gh, lh.y);             \
        lh.z = fmaf(a_.z, gh, lh.z); lh.w = fmaf(a_.w, gh, lh.w);             \
        hl.x = fmaf(d_.x, gl, hl.x); hl.y = fmaf(d_.y, gl, hl.y);             \
        hl.z = fmaf(d_.z, gl, hl.z); hl.w = fmaf(d_.w, gl, hl.w);             \
        hh.x = fmaf(d_.x, gh, hh.x); hh.y = fmaf(d_.y, gh, hh.y);             \
        hh.z = fmaf(d_.z, gh, hh.z); hh.w = fmaf(d_.w, gh, hh.w);             \
    }                                                                         \
    const int ho_ = st * TOH + uo_;                                           \
    if (ho_ < HO) {                                                           \
        const size_t p = (size_t)ho_ * HO + c0;                               \
        if (cg != NCG - 1) {                                                  \
            *(f4u*)(obase + p)           = ll;                                \
            *(f4u*)(obase + sub + p)     = lh;                                \
            *(f4u*)(obase + 2 * sub + p) = hl;                                \
            *(f4u*)(obase + 3 * sub + p) = hh;                                \
        } else {                                                              \
            _Pragma("unroll")                                                 \
            for (int o = 0; o < 3; ++o) {                                     \
                obase[p + o]           = ll[o];                               \
                obase[sub + p + o]     = lh[o];                               \
                obase[2 * sub + p + o] = hl[o];                               \
                obase[3 * sub + p + o] = hh[o];                               \
            }                                                                 \
        }                                                                     \
    }                                                                         \
} while (0)

    for (int ob = 0; ob < TOH / 4; ++ob) {
        STEP(0); STEP(1); STEP(2); STEP(3);
    }
#undef STEP
}

} // namespace

extern "C" void kernel_launch(void* const* d_in, const int* in_sizes, int n_in,
                              void* d_out, int out_size, void* d_ws, size_t ws_size,
                              hipStream_t stream) {
    const float* x = (const float*)d_in[0];
    float* out = (float*)d_out;
    const int items  = NBC * NS * NCG;      // 366,080
    const int blocks = items / 256;         // 1430 (exact)
    dwt2_db4_reg<<<blocks, 256, 0, stream>>>(x, out);
}